// Round 8
// baseline (134.456 us; speedup 1.0000x reference)
//
#include <hip/hip_runtime.h>
#include <hip/hip_bf16.h>

// Problem constants
#define NB   8
#define NC   256
#define HW   56
#define NPX  3136          // 56*56
#define RED  64
#define NG   16
#define GC   16
#define KS   7
#define KK   49
#define PADK 3
#define XPH  62            // padded rows: 3 + 56 + 3
#define XPW  64            // padded row stride
#define XPSLICE (XPH * XPW)   // 3968 floats per channel slice
#define TLS_STRIDE 72      // bf16 r-stride for transposed t tile
#define WLS_STRIDE 65      // f32 px-stride for wgt tile

typedef float f32x4 __attribute__((ext_vector_type(4)));
typedef short short8 __attribute__((ext_vector_type(8)));
typedef unsigned int u32x4 __attribute__((ext_vector_type(4)));

// ---------------------------------------------------------------------------
// K0a: zero only the BORDER of xpad (832 elems/slice); interior written by K1.
// ---------------------------------------------------------------------------
__global__ __launch_bounds__(256) void border_kernel(float* __restrict__ xpad) {
    int bc = blockIdx.x;                       // 0 .. NB*NC-1
    float* xd = xpad + (size_t)bc * XPSLICE;
#pragma unroll
    for (int e = threadIdx.x; e < 832; e += 256) {
        int row, col;
        if (e < 192)      { row = e >> 6;              col = e & 63; }
        else if (e < 384) { int f = e - 192; row = 59 + (f >> 6); col = f & 63; }
        else              { int f = e - 384; row = 3 + (f >> 3);
                            int c8 = f & 7;  col = (c8 < 3) ? c8 : 56 + c8; }
        xd[row * XPW + col] = 0.0f;
    }
}

// ---------------------------------------------------------------------------
// K0b: w2 [16g*49][64] fp32 -> w2bf [g][64m][64k] bf16 (rows 49..63 zero).
// ---------------------------------------------------------------------------
__global__ __launch_bounds__(256) void prep_w2_kernel(
    const float* __restrict__ w2, __hip_bfloat16* __restrict__ w2bf) {
    int g = blockIdx.x;                        // 0..15
#pragma unroll 4
    for (int e = threadIdx.x; e < 64 * 64; e += 256) {
        int m = e >> 6, k = e & 63;
        float v = (m < KK) ? w2[((size_t)g * KK + m) * RED + k] : 0.0f;
        w2bf[(size_t)g * 4096 + e] = __float2bfloat16(v);
    }
}

// ---------------------------------------------------------------------------
// K1: t = relu(bn1(conv1x1(x, w1))) -> bf16, AND scatter x into xpad interior.
// Grid 392 (XCD-swizzled) x 512 thr. c-loop unrolled 2x -> 32 loads in flight.
// ---------------------------------------------------------------------------
__global__ __launch_bounds__(512) void conv1_kernel(
    const float* __restrict__ x, const float* __restrict__ w1,
    const float* __restrict__ g1, const float* __restrict__ be1,
    const float* __restrict__ mu1, const float* __restrict__ var1,
    __hip_bfloat16* __restrict__ t, float* __restrict__ xpad) {
    int lane = threadIdx.x & 63;
    int wv   = __builtin_amdgcn_readfirstlane(threadIdx.x >> 6);  // 0..7 SGPR
    // XCD swizzle: 392 = 8 * 49; logical = b*49 + tile
    int wgid = blockIdx.x;
    int swz  = (wgid & 7) * 49 + (wgid >> 3);
    int tile = swz % 49;
    int b    = swz / 49;
    int px = tile * 64 + lane;
    int h = px / HW, w = px % HW;

    const float* xb = x + (size_t)b * NC * NPX + px;
    float* xpw = xpad + (size_t)b * NC * XPSLICE + (h + PADK) * XPW + (w + PADK);

    float acc[8];
#pragma unroll
    for (int j = 0; j < 8; ++j) acc[j] = 0.0f;

#pragma unroll 2
    for (int c0 = 0; c0 < NC; c0 += 16) {
        float xv[16];
#pragma unroll
        for (int i = 0; i < 16; ++i) xv[i] = xb[(size_t)(c0 + i) * NPX];
        if (wv == 0) {                         // wave-uniform branch
#pragma unroll
            for (int i = 0; i < 16; ++i)
                xpw[(size_t)(c0 + i) * XPSLICE] = xv[i];
        }
#pragma unroll
        for (int j = 0; j < 8; ++j) {
            const float* wrow = w1 + (wv * 8 + j) * NC + c0;   // s_load
#pragma unroll
            for (int i = 0; i < 16; ++i)
                acc[j] = fmaf(xv[i], wrow[i], acc[j]);
        }
    }

    __hip_bfloat16* tb = t + (size_t)b * RED * NPX + px;
#pragma unroll
    for (int j = 0; j < 8; ++j) {
        int o = wv * 8 + j;
        float inv = g1[o] * rsqrtf(var1[o] + 1e-5f);
        float v = acc[j] * inv + (be1[o] - mu1[o] * inv);
        tb[(size_t)o * NPX] = __float2bfloat16(fmaxf(v, 0.0f));
    }
}

// ---------------------------------------------------------------------------
// K2: fused conv2(MFMA) -> involution -> bn2 -> relu
// Grid 3136 (XCD-swizzled: each XCD owns one batch), block 512 = 8 waves.
// LDS: tls bf16 [64px][72r] + wls f32 [2g][49k][65px] = 34.7 KB.
// Phase A (MFMA): wave (gl,ni): wgt[4x16 m][16 px], bias folded into C-write.
// Phase B: wgt[49] hoisted to VGPRs (49x ds_read_b32, 2-way = free); per
//   channel ALL 14 f32x4 x-loads issued up-front (deep MLP), 49 FMA in 4
//   chains, bn2+relu, coalesced store. All arrays statically indexed.
// __launch_bounds__(512,4): VGPR cap 128 = 4 waves/EU, 2 blocks/CU.
// ---------------------------------------------------------------------------
__global__ __launch_bounds__(512, 4) void involution_kernel(
    const float* __restrict__ xpad, const __hip_bfloat16* __restrict__ t,
    const __hip_bfloat16* __restrict__ w2bf, const float* __restrict__ b2,
    const float* __restrict__ g2, const float* __restrict__ be2,
    const float* __restrict__ mu2, const float* __restrict__ var2,
    float* __restrict__ out) {
    __shared__ __align__(16) short tls[64 * TLS_STRIDE];   // bf16 [px][r]
    __shared__ float wls[2 * KK * WLS_STRIDE];             // f32  [gl][k][px]

    int tid  = threadIdx.x;
    int lane = tid & 63;
    int wv   = __builtin_amdgcn_readfirstlane(tid >> 6);   // 0..7 SGPR
    // XCD swizzle: 3136 = 8 * 392; logical = b*392 + gp*49 + tile
    int wgid = blockIdx.x;
    int swz  = (wgid & 7) * 392 + (wgid >> 3);
    int tile = swz % 49;
    int gp   = (swz / 49) & 7;
    int b    = swz / 392;
    int px0 = tile * 64;
    int px = px0 + lane;
    int h = px / HW, w = px % HW;

    // ---- stage t tile transposed: one ds_write_b128 per lane ----
    const unsigned short* tb =
        (const unsigned short*)t + (size_t)b * RED * NPX + px0;
    {
        unsigned int pk[4];
#pragma unroll
        for (int j = 0; j < 4; ++j) {
            unsigned int lo = tb[(size_t)(wv * 8 + 2 * j)     * NPX + lane];
            unsigned int hi = tb[(size_t)(wv * 8 + 2 * j + 1) * NPX + lane];
            pk[j] = lo | (hi << 16);
        }
        u32x4 v = {pk[0], pk[1], pk[2], pk[3]};
        *(u32x4*)&tls[lane * TLS_STRIDE + wv * 8] = v;
    }
    __syncthreads();

    int gl = wv >> 2;                          // local group 0/1 (SGPR)
    int g  = gp * 2 + gl;
    const float* bg = b2 + (size_t)g * KK;     // wave-uniform -> s_load

    // ---- phase A: MFMA wgt = w2g[49x64] . t[64x64px] (+bias) ----
    {
        int ni = wv & 3;                       // N-tile 0..3 (SGPR)
        int l15 = lane & 15, l4 = lane >> 4;
        const short* tp = tls + (ni * 16 + l15) * TLS_STRIDE + l4 * 8;
        short8 bfr0 = *(const short8*)(tp);
        short8 bfr1 = *(const short8*)(tp + 32);

        const short* wA = (const short*)w2bf + (size_t)g * 4096;
        f32x4 acc0 = {0,0,0,0}, acc1 = {0,0,0,0}, acc2 = {0,0,0,0}, acc3 = {0,0,0,0};
#pragma unroll
        for (int mt = 0; mt < 4; ++mt) {
            const short* ap = wA + (mt * 16 + l15) * 64 + l4 * 8;
            short8 a0 = *(const short8*)(ap);
            short8 a1 = *(const short8*)(ap + 32);
            f32x4 a = (mt == 0) ? acc0 : (mt == 1) ? acc1 : (mt == 2) ? acc2 : acc3;
            a = __builtin_amdgcn_mfma_f32_16x16x32_bf16(a0, bfr0, a, 0, 0, 0);
            a = __builtin_amdgcn_mfma_f32_16x16x32_bf16(a1, bfr1, a, 0, 0, 0);
            if (mt == 0) acc0 = a; else if (mt == 1) acc1 = a;
            else if (mt == 2) acc2 = a; else acc3 = a;
        }
        float* wl = wls + gl * (KK * WLS_STRIDE) + ni * 16 + l15;
#pragma unroll
        for (int mt = 0; mt < 4; ++mt) {
            f32x4 a = (mt == 0) ? acc0 : (mt == 1) ? acc1 : (mt == 2) ? acc2 : acc3;
#pragma unroll
            for (int r = 0; r < 4; ++r) {
                int k = mt * 16 + l4 * 4 + r;
                if (k < KK) wl[k * WLS_STRIDE] = a[r] + bg[k];  // bias folded
            }
        }
    }
    __syncthreads();

    // ---- phase B: involution + bn2 + relu ----
    int q = wv & 3;
    int cl0 = q * 4;
    const float* wlg = wls + gl * (KK * WLS_STRIDE);
    const float* xgb = xpad + ((size_t)b * NC + (size_t)(g * GC + cl0)) * XPSLICE
                     + h * XPW + w;
    float* ob = out + ((size_t)b * NC + (size_t)(g * GC + cl0)) * NPX + px;

    // hoist wgt[49] into registers: stride-65 dword reads -> 2-way, free
    float wgt[KK];
#pragma unroll
    for (int k = 0; k < KK; ++k) wgt[k] = wlg[k * WLS_STRIDE + lane];

#pragma unroll 1
    for (int cl = 0; cl < 4; ++cl) {
        const float* xc = xgb + (size_t)cl * XPSLICE;
        // issue ALL 14 loads up-front (independent -> 14 VMEM in flight)
        f32x4 xr0[KS], xr1[KS];
#pragma unroll
        for (int i = 0; i < KS; ++i) {
            xr0[i] = *(const f32x4*)(xc + i * XPW);       // taps 0..3
            xr1[i] = *(const f32x4*)(xc + i * XPW + 4);   // taps 4..6 (+spare)
        }
        float s0 = 0.f, s1 = 0.f, s2 = 0.f, s3 = 0.f;
#pragma unroll
        for (int i = 0; i < KS; ++i) {
            s0 = fmaf(wgt[i * KS + 0], xr0[i].x, s0);
            s1 = fmaf(wgt[i * KS + 1], xr0[i].y, s1);
            s2 = fmaf(wgt[i * KS + 2], xr0[i].z, s2);
            s3 = fmaf(wgt[i * KS + 3], xr0[i].w, s3);
            s0 = fmaf(wgt[i * KS + 4], xr1[i].x, s0);
            s1 = fmaf(wgt[i * KS + 5], xr1[i].y, s1);
            s2 = fmaf(wgt[i * KS + 6], xr1[i].z, s2);
        }
        float acc = (s0 + s1) + (s2 + s3);

        int c = g * GC + cl0 + cl;
        float inv = g2[c] * rsqrtf(var2[c] + 1e-5f);
        float v = acc * inv + (be2[c] - mu2[c] * inv);
        ob[(size_t)cl * NPX] = fmaxf(v, 0.0f);
    }
}

// ---------------------------------------------------------------------------
extern "C" void kernel_launch(void* const* d_in, const int* in_sizes, int n_in,
                              void* d_out, int out_size, void* d_ws, size_t ws_size,
                              hipStream_t stream) {
    const float* x    = (const float*)d_in[0];
    const float* w1   = (const float*)d_in[1];
    const float* g1   = (const float*)d_in[2];
    const float* be1  = (const float*)d_in[3];
    const float* mu1  = (const float*)d_in[4];
    const float* var1 = (const float*)d_in[5];
    const float* w2   = (const float*)d_in[6];
    const float* b2   = (const float*)d_in[7];
    const float* g2   = (const float*)d_in[8];
    const float* be2  = (const float*)d_in[9];
    const float* mu2  = (const float*)d_in[10];
    const float* var2 = (const float*)d_in[11];
    float* outp = (float*)d_out;

    // ws: xpad f32 (32.5 MB) | t bf16 (3.2 MB) | w2bf bf16 (128 KB)
    float* xpad = (float*)d_ws;
    char* p = (char*)d_ws + (size_t)NB * NC * XPSLICE * sizeof(float);
    __hip_bfloat16* t = (__hip_bfloat16*)p;
    p += (size_t)NB * RED * NPX * sizeof(__hip_bfloat16);
    __hip_bfloat16* w2bf = (__hip_bfloat16*)p;

    prep_w2_kernel<<<NG, 256, 0, stream>>>(w2, w2bf);
    border_kernel<<<NB * NC, 256, 0, stream>>>(xpad);
    conv1_kernel<<<392, 512, 0, stream>>>(
        x, w1, g1, be1, mu1, var1, t, xpad);
    involution_kernel<<<3136, 512, 0, stream>>>(
        xpad, t, w2bf, b2, g2, be2, mu2, var2, outp);
}

// Round 9
// 91.641 us; speedup vs baseline: 1.4672x; 1.4672x over previous
//
#include <hip/hip_runtime.h>
#include <hip/hip_bf16.h>

// Problem constants
#define NB   8
#define NC   256
#define HW   56
#define NPX  3136          // 56*56
#define RED  64
#define NG   16
#define GC   16
#define KS   7
#define KK   49
#define PADK 3
#define XPH  62            // padded rows: 3 + 56 + 3
#define XPW  64            // padded row stride
#define XPSLICE (XPH * XPW)   // 3968 floats per channel slice
#define WLS_STRIDE 68      // f32 px-stride for wgt tile (16B-aligned quads)

typedef float f32x4 __attribute__((ext_vector_type(4)));
typedef short short8 __attribute__((ext_vector_type(8)));

// ---------------------------------------------------------------------------
// K0a: zero only the BORDER of xpad (832 elems/slice); interior written by K1.
// ---------------------------------------------------------------------------
__global__ __launch_bounds__(256) void border_kernel(float* __restrict__ xpad) {
    int bc = blockIdx.x;                       // 0 .. NB*NC-1
    float* xd = xpad + (size_t)bc * XPSLICE;
#pragma unroll
    for (int e = threadIdx.x; e < 832; e += 256) {
        int row, col;
        if (e < 192)      { row = e >> 6;              col = e & 63; }
        else if (e < 384) { int f = e - 192; row = 59 + (f >> 6); col = f & 63; }
        else              { int f = e - 384; row = 3 + (f >> 3);
                            int c8 = f & 7;  col = (c8 < 3) ? c8 : 56 + c8; }
        xd[row * XPW + col] = 0.0f;
    }
}

// ---------------------------------------------------------------------------
// K0b: w2 [16g*49][64] fp32 -> w2bf [g][64m][64k] bf16 (rows 49..63 zero).
// ---------------------------------------------------------------------------
__global__ __launch_bounds__(256) void prep_w2_kernel(
    const float* __restrict__ w2, __hip_bfloat16* __restrict__ w2bf) {
    int g = blockIdx.x;                        // 0..15
#pragma unroll 4
    for (int e = threadIdx.x; e < 64 * 64; e += 256) {
        int m = e >> 6, k = e & 63;
        float v = (m < KK) ? w2[((size_t)g * KK + m) * RED + k] : 0.0f;
        w2bf[(size_t)g * 4096 + e] = __float2bfloat16(v);
    }
}

// ---------------------------------------------------------------------------
// K1: t = relu(bn1(conv1x1(x, w1))) -> bf16, AND scatter x into xpad interior.
// Grid 784 1D (XCD-swizzled, 8x98) x 256 thr (4 waves): (49 tiles, 2 rq-halves,
// 8 b). 3.06 blocks/CU for balance; halves re-read x via L2.
// ---------------------------------------------------------------------------
__global__ __launch_bounds__(256) void conv1_kernel(
    const float* __restrict__ x, const float* __restrict__ w1,
    const float* __restrict__ g1, const float* __restrict__ be1,
    const float* __restrict__ mu1, const float* __restrict__ var1,
    __hip_bfloat16* __restrict__ t, float* __restrict__ xpad) {
    int lane = threadIdx.x & 63;
    int wv   = __builtin_amdgcn_readfirstlane(threadIdx.x >> 6);  // 0..3 SGPR
    // XCD swizzle: 784 = 8 * 98; logical = b*98 + half*49 + tile
    int wgid = blockIdx.x;
    int swz  = (wgid & 7) * 98 + (wgid >> 3);
    int b    = swz / 98;
    int rem  = swz % 98;
    int half = rem / 49;
    int tile = rem % 49;
    int rq = half * 4 + wv;                    // 0..7 -> outputs rq*8..rq*8+7
    int px = tile * 64 + lane;
    int h = px / HW, w = px % HW;

    const float* xb = x + (size_t)b * NC * NPX + px;
    float* xpw = xpad + (size_t)b * NC * XPSLICE + (h + PADK) * XPW + (w + PADK);

    float acc[8];
#pragma unroll
    for (int j = 0; j < 8; ++j) acc[j] = 0.0f;

#pragma unroll 2
    for (int c0 = 0; c0 < NC; c0 += 16) {
        float xv[16];
#pragma unroll
        for (int i = 0; i < 16; ++i) xv[i] = xb[(size_t)(c0 + i) * NPX];
        if (half == 0 && wv == 0) {            // block+wave-uniform branch
#pragma unroll
            for (int i = 0; i < 16; ++i)
                xpw[(size_t)(c0 + i) * XPSLICE] = xv[i];
        }
#pragma unroll
        for (int j = 0; j < 8; ++j) {
            const float* wrow = w1 + (rq * 8 + j) * NC + c0;   // s_load
#pragma unroll
            for (int i = 0; i < 16; ++i)
                acc[j] = fmaf(xv[i], wrow[i], acc[j]);
        }
    }

    __hip_bfloat16* tb = t + (size_t)b * RED * NPX + px;
#pragma unroll
    for (int j = 0; j < 8; ++j) {
        int o = rq * 8 + j;
        float inv = g1[o] * rsqrtf(var1[o] + 1e-5f);
        float v = acc[j] * inv + (be1[o] - mu1[o] * inv);
        tb[(size_t)o * NPX] = __float2bfloat16(fmaxf(v, 0.0f));
    }
}

// ---------------------------------------------------------------------------
// K2: fused conv2(MFMA) -> involution -> bn2 -> relu.  ONE group per block.
// Grid 6272 1D (XCD-swizzled 8x784: each XCD owns one batch), 256 thr (4 waves).
// LDS: xtap f32 [16ch][8rows][64col] (32 KB) + wls f32 [49][68] (13.3 KB)
//      = 45.6 KB -> 3 blocks/CU.
// Step 1 (T14): issue 8 f32x4 xtap loads from xpad (global->reg), write later.
// Step 2 (phase A): MFMA wgt = w2g . t-tile. B-frags gathered DIRECTLY from
//   global t (16 ushort loads, L2-hot) - no tls. C+bias -> wls.
// Step 3: reg->LDS xtap writes, one barrier.
// Step 4 (phase B): lane = (ch, px-quad). ALL tap+wgt reads from LDS as
//   aligned b128 (w0 % 4 == 0; quads never straddle pixel rows). 70 LDS reads
//   + 196 FMA per lane, f32x4 coalesced store.
// ---------------------------------------------------------------------------
__global__ __launch_bounds__(256, 3) void involution_kernel(
    const float* __restrict__ xpad, const __hip_bfloat16* __restrict__ t,
    const __hip_bfloat16* __restrict__ w2bf, const float* __restrict__ b2,
    const float* __restrict__ g2, const float* __restrict__ be2,
    const float* __restrict__ mu2, const float* __restrict__ var2,
    float* __restrict__ out) {
    __shared__ __align__(16) float xtap[GC * 8 * 64];      // 32 KB
    __shared__ __align__(16) float wls[KK * WLS_STRIDE];   // 13.3 KB

    int tid  = threadIdx.x;
    int lane = tid & 63;
    int wv   = __builtin_amdgcn_readfirstlane(tid >> 6);   // 0..3 = ni (SGPR)
    // XCD swizzle: 6272 = 8 * 784; logical = b*784 + g*49 + tile
    int wgid = blockIdx.x;
    int swz  = (wgid & 7) * 784 + (wgid >> 3);
    int tile = swz % 49;
    int g    = (swz / 49) & 15;
    int b    = swz / 784;
    int px0 = tile * 64;
    int h0  = px0 / HW;                        // first pixel-row of tile

    const float* xpb = xpad + ((size_t)b * NC + (size_t)g * GC) * XPSLICE;

    // ---- step 1: issue xtap global loads (held in regs across phase A) ----
    f32x4 xr[8];
#pragma unroll
    for (int u = 0; u < 8; ++u) {
        int cid = u * 256 + tid;               // 0..2047 16B-chunks
        int row = cid >> 4;                    // ch*8 + ri  (0..127)
        int c4  = cid & 15;
        int ch = row >> 3, ri = row & 7;
        xr[u] = *(const f32x4*)(xpb + (size_t)ch * XPSLICE + (h0 + ri) * XPW + c4 * 4);
    }

    // ---- step 2: phase A MFMA  wgt[49x64px] = w2g[49x64r] . t[64r x 64px] ----
    {
        int l15 = lane & 15, l4 = lane >> 4;
        int pxc = px0 + wv * 16 + l15;
        const unsigned short* tg =
            (const unsigned short*)t + (size_t)b * RED * NPX + pxc;
        short8 bfr0, bfr1;
#pragma unroll
        for (int i = 0; i < 8; ++i) {
            bfr0[i] = (short)tg[(size_t)(l4 * 8 + i) * NPX];
            bfr1[i] = (short)tg[(size_t)(32 + l4 * 8 + i) * NPX];
        }

        const short* wA = (const short*)w2bf + (size_t)g * 4096;
        const float* bg = b2 + (size_t)g * KK;
        f32x4 acc0 = {0,0,0,0}, acc1 = {0,0,0,0}, acc2 = {0,0,0,0}, acc3 = {0,0,0,0};
#pragma unroll
        for (int mt = 0; mt < 4; ++mt) {
            const short* ap = wA + (mt * 16 + l15) * 64 + l4 * 8;
            short8 a0 = *(const short8*)(ap);
            short8 a1 = *(const short8*)(ap + 32);
            f32x4 a = (mt == 0) ? acc0 : (mt == 1) ? acc1 : (mt == 2) ? acc2 : acc3;
            a = __builtin_amdgcn_mfma_f32_16x16x32_bf16(a0, bfr0, a, 0, 0, 0);
            a = __builtin_amdgcn_mfma_f32_16x16x32_bf16(a1, bfr1, a, 0, 0, 0);
            if (mt == 0) acc0 = a; else if (mt == 1) acc1 = a;
            else if (mt == 2) acc2 = a; else acc3 = a;
        }
        // C write: wls[k][px], k = mt*16 + l4*4 + r, px = wv*16 + l15
        float* wl = wls + wv * 16 + l15;
#pragma unroll
        for (int mt = 0; mt < 4; ++mt) {
            f32x4 a = (mt == 0) ? acc0 : (mt == 1) ? acc1 : (mt == 2) ? acc2 : acc3;
#pragma unroll
            for (int r = 0; r < 4; ++r) {
                int k = mt * 16 + l4 * 4 + r;
                if (k < KK) wl[k * WLS_STRIDE] = a[r] + bg[k];  // bias folded
            }
        }
    }

    // ---- step 3: write xtap regs to LDS, single barrier ----
#pragma unroll
    for (int u = 0; u < 8; ++u) {
        int cid = u * 256 + tid;
        int row = cid >> 4, c4 = cid & 15;
        *(f32x4*)&xtap[row * 64 + c4 * 4] = xr[u];
    }
    __syncthreads();

    // ---- step 4: phase B, lane = (ch, 4-px quad), all-LDS taps ----
    int quad = tid & 15;                       // 0..15
    int ch   = tid >> 4;                       // 0..15
    int pxl  = quad * 4;                       // local px of quad start
    int px_a = px0 + pxl;
    int lh   = px_a / HW - h0;                 // 0 or 1 (quads don't straddle)
    int w0   = px_a % HW;                      // multiple of 4

    const float* xrow0 = xtap + (ch * 8 + lh) * 64 + w0;
    float acc[4] = {0.0f, 0.0f, 0.0f, 0.0f};
#pragma unroll
    for (int i = 0; i < KS; ++i) {
        f32x4 c0 = *(const f32x4*)(xrow0 + i * 64);
        f32x4 c1 = *(const f32x4*)(xrow0 + i * 64 + 4);
        f32x4 c2 = *(const f32x4*)(xrow0 + i * 64 + 8);
        float cc[12] = {c0.x, c0.y, c0.z, c0.w,
                        c1.x, c1.y, c1.z, c1.w,
                        c2.x, c2.y, c2.z, c2.w};
#pragma unroll
        for (int j = 0; j < KS; ++j) {
            f32x4 wq = *(const f32x4*)&wls[(i * KS + j) * WLS_STRIDE + pxl];
            acc[0] = fmaf(wq.x, cc[j + 0], acc[0]);
            acc[1] = fmaf(wq.y, cc[j + 1], acc[1]);
            acc[2] = fmaf(wq.z, cc[j + 2], acc[2]);
            acc[3] = fmaf(wq.w, cc[j + 3], acc[3]);
        }
    }

    int c_ = g * GC + ch;
    float inv = g2[c_] * rsqrtf(var2[c_] + 1e-5f);
    float off = be2[c_] - mu2[c_] * inv;
    f32x4 o;
#pragma unroll
    for (int e = 0; e < 4; ++e) o[e] = fmaxf(acc[e] * inv + off, 0.0f);
    *(f32x4*)(out + ((size_t)b * NC + c_) * NPX + px_a) = o;
}

// ---------------------------------------------------------------------------
extern "C" void kernel_launch(void* const* d_in, const int* in_sizes, int n_in,
                              void* d_out, int out_size, void* d_ws, size_t ws_size,
                              hipStream_t stream) {
    const float* x    = (const float*)d_in[0];
    const float* w1   = (const float*)d_in[1];
    const float* g1   = (const float*)d_in[2];
    const float* be1  = (const float*)d_in[3];
    const float* mu1  = (const float*)d_in[4];
    const float* var1 = (const float*)d_in[5];
    const float* w2   = (const float*)d_in[6];
    const float* b2   = (const float*)d_in[7];
    const float* g2   = (const float*)d_in[8];
    const float* be2  = (const float*)d_in[9];
    const float* mu2  = (const float*)d_in[10];
    const float* var2 = (const float*)d_in[11];
    float* outp = (float*)d_out;

    // ws: xpad f32 (32.5 MB) | t bf16 (3.2 MB) | w2bf bf16 (128 KB)
    float* xpad = (float*)d_ws;
    char* p = (char*)d_ws + (size_t)NB * NC * XPSLICE * sizeof(float);
    __hip_bfloat16* t = (__hip_bfloat16*)p;
    p += (size_t)NB * RED * NPX * sizeof(__hip_bfloat16);
    __hip_bfloat16* w2bf = (__hip_bfloat16*)p;

    prep_w2_kernel<<<NG, 256, 0, stream>>>(w2, w2bf);
    border_kernel<<<NB * NC, 256, 0, stream>>>(xpad);
    conv1_kernel<<<784, 256, 0, stream>>>(
        x, w1, g1, be1, mu1, var1, t, xpad);
    involution_kernel<<<6272, 256, 0, stream>>>(
        xpad, t, w2bf, b2, g2, be2, mu2, var2, outp);
}